// Round 5
// baseline (593.841 us; speedup 1.0000x reference)
//
#include <hip/hip_runtime.h>
#include <hip/hip_bf16.h>

#define D_DIM 256
#define MARGIN 0.12f

typedef __attribute__((ext_vector_type(8))) _Float16 half8v;   // 8 x f16 fragment (4 VGPR)
typedef __attribute__((ext_vector_type(4))) _Float16 half4v;
typedef __attribute__((ext_vector_type(4))) float floatx4;     // MFMA accumulator

// ---------------- ws layout ----------------
// EHF_OFF = 0          : emb_f16 (K*256 f16 = 512KB)
// ESQ_OFF = 512K       : esq     (K floats)
// CNT_OFF = 512K+4K    : counts  (K floats)
// LOSS_OFF= 512K+8K    : lossAcc (float)
// FLC_OFF = 512K+8K+64 : flagCount (int)
// FLG_OFF = 512K+16K   : flags   (N ints)

// emb -> f16, exact fp32 ||e||^2, and zero counts/lossAcc/flagCount (replaces memset).
__global__ __launch_bounds__(64) void prep_kernel(const float* __restrict__ emb,
                                                  _Float16* __restrict__ ehf,
                                                  float* __restrict__ esq,
                                                  float* __restrict__ counts,
                                                  float* __restrict__ lossAcc,
                                                  int* __restrict__ flagCount) {
    int k = blockIdx.x;
    int lane = threadIdx.x;
    float4 v = reinterpret_cast<const float4*>(emb + (size_t)k * D_DIM)[lane];
    half4v h;
    h[0] = (_Float16)v.x; h[1] = (_Float16)v.y; h[2] = (_Float16)v.z; h[3] = (_Float16)v.w;
    *reinterpret_cast<half4v*>(ehf + (size_t)k * D_DIM + lane * 4) = h;
    float s = fmaf(v.x, v.x, fmaf(v.y, v.y, fmaf(v.z, v.z, v.w * v.w)));
    #pragma unroll
    for (int off = 32; off; off >>= 1) s += __shfl_down(s, off, 64);
    if (lane == 0) {
        esq[k] = s;
        counts[k] = 0.f;
        if (k == 0) { *lossAcc = 0.f; *flagCount = 0; }
    }
}

// Stage one 16-code chunk (16 x 256 f16 = 8KB) global->LDS with XOR-swizzled source.
// LDS stays linear (global_load_lds requirement); physical 16B slot p of code row c
// holds global slot (p ^ (c&7)); ds_read applies the same XOR -> conflict-free.
static __device__ __forceinline__ void stage_chunk16(const _Float16* __restrict__ ehf,
                                                     char* lbuf, int c0, int tid) {
    #pragma unroll
    for (int i = 0; i < 2; ++i) {
        int o = i * 4096 + tid * 16;   // per-lane LDS byte offset (linear, wave-uniform base + lane*16)
        int code = o >> 9;             // 0..15
        int p = (o >> 4) & 31;         // 16B slot within 512B code row
        int srcSlot = p ^ (code & 7);
        const _Float16* src = ehf + (size_t)(c0 + code) * D_DIM + srcSlot * 8;
        __builtin_amdgcn_global_load_lds(
            (const __attribute__((address_space(1))) unsigned int*)src,
            (__attribute__((address_space(3))) unsigned int*)(lbuf + o),
            16, 0, 0);
    }
}

// Fused: f16-MFMA scores + argmin + (unflagged rows) gather/ST-output/loss/counts.
// 4 waves x 32 rows = 128 rows/block, 1024 blocks (4 blocks/CU -> phase staggering).
// B double-buffered in LDS, 16-code chunks, 64 chunks.
__global__ __launch_bounds__(256, 4) void argmin_fused_kernel(
    const float* __restrict__ z, const float* __restrict__ emb,
    const _Float16* __restrict__ ehf, const float* __restrict__ esq,
    float* __restrict__ qout, float* __restrict__ counts, float* __restrict__ lossAcc,
    int* __restrict__ flags, int* __restrict__ flagCount, int K)
{
    __shared__ char bstage[2][8192];

    const int tid = threadIdx.x;
    const int lane = tid & 63;
    const int wid = tid >> 6;
    const int l15 = lane & 15;
    const int lk8 = (lane >> 4) << 3;     // k-offset within 32-dim step: 0,8,16,24
    const int rowbase = blockIdx.x * 128 + wid * 32;

    stage_chunk16(ehf, &bstage[0][0], 0, tid);

    // ---- load z rows, convert to f16 fragments (held whole loop) ----
    half8v a0[8], a1[8];
    {
        const float* zr0 = z + (size_t)(rowbase + l15) * D_DIM + lk8;
        const float* zr1 = z + (size_t)(rowbase + 16 + l15) * D_DIM + lk8;
        #pragma unroll
        for (int ks = 0; ks < 8; ++ks) {
            float4 v0 = *reinterpret_cast<const float4*>(zr0 + ks * 32);
            float4 v1 = *reinterpret_cast<const float4*>(zr0 + ks * 32 + 4);
            half8v h;
            h[0] = (_Float16)v0.x; h[1] = (_Float16)v0.y;
            h[2] = (_Float16)v0.z; h[3] = (_Float16)v0.w;
            h[4] = (_Float16)v1.x; h[5] = (_Float16)v1.y;
            h[6] = (_Float16)v1.z; h[7] = (_Float16)v1.w;
            a0[ks] = h;
            float4 w0 = *reinterpret_cast<const float4*>(zr1 + ks * 32);
            float4 w1 = *reinterpret_cast<const float4*>(zr1 + ks * 32 + 4);
            half8v g;
            g[0] = (_Float16)w0.x; g[1] = (_Float16)w0.y;
            g[2] = (_Float16)w0.z; g[3] = (_Float16)w0.w;
            g[4] = (_Float16)w1.x; g[5] = (_Float16)w1.y;
            g[6] = (_Float16)w1.z; g[7] = (_Float16)w1.w;
            a1[ks] = g;
        }
    }

    float best1[2][4], best2[2][4];
    int bidx[2][4];
    #pragma unroll
    for (int mi = 0; mi < 2; ++mi)
        #pragma unroll
        for (int r = 0; r < 4; ++r) { best1[mi][r] = 3.0e38f; best2[mi][r] = 3.0e38f; bidx[mi][r] = 0; }

    const int h3 = l15 & 7;   // swizzle key (code row = l15)
    const int NT = K / 16;    // 64 chunks

    for (int t = 0; t < NT; ++t) {
        __syncthreads();      // buf[t&1] staged; prior reads of buf[(t+1)&1] done
        if (t + 1 < NT) stage_chunk16(ehf, &bstage[(t + 1) & 1][0], (t + 1) * 16, tid);

        const char* lb = &bstage[t & 1][0];
        floatx4 acc0 = (floatx4){0.f, 0.f, 0.f, 0.f};
        floatx4 acc1 = (floatx4){0.f, 0.f, 0.f, 0.f};

        #pragma unroll
        for (int ks = 0; ks < 8; ++ks) {
            int po = ((((lane >> 4) + 4 * ks)) ^ h3) << 4;
            half8v b0 = *reinterpret_cast<const half8v*>(lb + l15 * 512 + po);
            acc0 = __builtin_amdgcn_mfma_f32_16x16x32_f16(a0[ks], b0, acc0, 0, 0, 0);
            acc1 = __builtin_amdgcn_mfma_f32_16x16x32_f16(a1[ks], b0, acc1, 0, 0, 0);
        }

        int c0 = t * 16;
        float e0 = esq[c0 + l15];   // L1-hot (1024 floats total)
        #pragma unroll
        for (int r = 0; r < 4; ++r) {
            float s0 = fmaf(-2.f, acc0[r], e0);
            if (s0 < best1[0][r]) { best2[0][r] = best1[0][r]; best1[0][r] = s0; bidx[0][r] = c0 + l15; }
            else best2[0][r] = fminf(best2[0][r], s0);
            float s1 = fmaf(-2.f, acc1[r], e0);
            if (s1 < best1[1][r]) { best2[1][r] = best1[1][r]; best1[1][r] = s1; bidx[1][r] = c0 + l15; }
            else best2[1][r] = fminf(best2[1][r], s1);
        }
    }

    // 16-lane symmetric butterfly: afterwards ALL lanes hold final (min1,min2,idx)
    // for rows rowbase + mi*16 + (lane>>4)*4 + r.
    int packed[2][4];
    #pragma unroll
    for (int mi = 0; mi < 2; ++mi) {
        #pragma unroll
        for (int r = 0; r < 4; ++r) {
            float a1v = best1[mi][r], b2 = best2[mi][r];
            int i = bidx[mi][r];
            #pragma unroll
            for (int off = 8; off; off >>= 1) {
                float oa = __shfl_xor(a1v, off, 16);
                float ob = __shfl_xor(b2, off, 16);
                int oi = __shfl_xor(i, off, 16);
                float m2 = fminf(fmaxf(a1v, oa), fminf(b2, ob));
                if (oa < a1v || (oa == a1v && oi < i)) { a1v = oa; i = oi; }
                b2 = m2;
            }
            bool flg = (b2 - a1v < MARGIN);
            packed[mi][r] = i | (flg ? (int)0x80000000 : 0);
            if (l15 == 0 && flg) {
                int row = rowbase + mi * 16 + (lane >> 4) * 4 + r;
                int p = atomicAdd(flagCount, 1);
                flags[p] = row;
            }
        }
    }

    // Fused epilogue: unflagged rows -> gather e[k], q = z + (e - z), loss + counts.
    // Flagged rows fully handled by rescore_kernel.
    float ls = 0.f;
    #pragma unroll
    for (int j = 0; j < 32; ++j) {
        const int mi = j >> 4;
        const int r = j & 3;
        const int srcLane = ((j & 15) >> 2) << 4;
        int pk = __shfl(packed[mi][r], srcLane, 64);   // wave-uniform
        if (pk >= 0) {
            int k = pk;
            int row = rowbase + j;
            float4 zv = *reinterpret_cast<const float4*>(z + (size_t)row * D_DIM + lane * 4);
            float4 ev = *reinterpret_cast<const float4*>(emb + (size_t)k * D_DIM + lane * 4);
            float4 df, o;
            df.x = ev.x - zv.x; df.y = ev.y - zv.y; df.z = ev.z - zv.z; df.w = ev.w - zv.w;
            o.x = zv.x + df.x; o.y = zv.y + df.y; o.z = zv.z + df.z; o.w = zv.w + df.w;
            *reinterpret_cast<float4*>(qout + (size_t)row * D_DIM + lane * 4) = o;
            ls = fmaf(df.x, df.x, ls); ls = fmaf(df.y, df.y, ls);
            ls = fmaf(df.z, df.z, ls); ls = fmaf(df.w, df.w, ls);
            if (lane == 0) atomicAdd(&counts[k], 1.0f);
        }
    }
    #pragma unroll
    for (int off = 32; off; off >>= 1) ls += __shfl_down(ls, off, 64);
    if (lane == 0) atomicAdd(lossAcc, ls);
}

// Exact fp32 rescore (reference-matching arithmetic) + full epilogue for flagged rows.
// d-outer / 4-codes-inner: 4 independent L2 load streams per thread.
__global__ __launch_bounds__(256) void rescore_kernel(
    const float* __restrict__ z, const float* __restrict__ emb,
    const float* __restrict__ esq,
    const int* __restrict__ flags, const int* __restrict__ flagCount,
    float* __restrict__ qout, float* __restrict__ counts, float* __restrict__ lossAcc,
    int K)
{
    __shared__ float zs[D_DIM];
    __shared__ float rv[256];
    __shared__ int ri[256];
    const int tid = threadIdx.x;
    const int cnt = *flagCount;
    for (int fi = blockIdx.x; fi < cnt; fi += gridDim.x) {
        int row = flags[fi];
        __syncthreads();
        zs[tid] = z[(size_t)row * D_DIM + tid];
        __syncthreads();
        const float* er = emb + (size_t)(tid * 4) * D_DIM;
        float d0 = 0.f, d1 = 0.f, d2 = 0.f, d3 = 0.f;
        const float4* zs4 = reinterpret_cast<const float4*>(zs);
        #pragma unroll 4
        for (int d = 0; d < D_DIM; d += 4) {
            float4 zv = zs4[d >> 2];
            float4 e0 = *reinterpret_cast<const float4*>(er + d);
            float4 e1 = *reinterpret_cast<const float4*>(er + D_DIM + d);
            float4 e2 = *reinterpret_cast<const float4*>(er + 2 * D_DIM + d);
            float4 e3 = *reinterpret_cast<const float4*>(er + 3 * D_DIM + d);
            d0 = fmaf(zv.x, e0.x, d0); d0 = fmaf(zv.y, e0.y, d0);
            d0 = fmaf(zv.z, e0.z, d0); d0 = fmaf(zv.w, e0.w, d0);
            d1 = fmaf(zv.x, e1.x, d1); d1 = fmaf(zv.y, e1.y, d1);
            d1 = fmaf(zv.z, e1.z, d1); d1 = fmaf(zv.w, e1.w, d1);
            d2 = fmaf(zv.x, e2.x, d2); d2 = fmaf(zv.y, e2.y, d2);
            d2 = fmaf(zv.z, e2.z, d2); d2 = fmaf(zv.w, e2.w, d2);
            d3 = fmaf(zv.x, e3.x, d3); d3 = fmaf(zv.y, e3.y, d3);
            d3 = fmaf(zv.z, e3.z, d3); d3 = fmaf(zv.w, e3.w, d3);
        }
        float s0 = fmaf(-2.f, d0, esq[tid * 4]);
        float s1 = fmaf(-2.f, d1, esq[tid * 4 + 1]);
        float s2 = fmaf(-2.f, d2, esq[tid * 4 + 2]);
        float s3 = fmaf(-2.f, d3, esq[tid * 4 + 3]);
        float bv = s0; int bi = tid * 4;
        if (s1 < bv) { bv = s1; bi = tid * 4 + 1; }
        if (s2 < bv) { bv = s2; bi = tid * 4 + 2; }
        if (s3 < bv) { bv = s3; bi = tid * 4 + 3; }
        rv[tid] = bv; ri[tid] = bi;
        __syncthreads();
        for (int s2r = 128; s2r; s2r >>= 1) {
            if (tid < s2r) {
                if (rv[tid + s2r] < rv[tid] || (rv[tid + s2r] == rv[tid] && ri[tid + s2r] < ri[tid])) {
                    rv[tid] = rv[tid + s2r]; ri[tid] = ri[tid + s2r];
                }
            }
            __syncthreads();
        }
        int k = ri[0];
        // epilogue for this flagged row
        float zvv = zs[tid];
        float evv = emb[(size_t)k * D_DIM + tid];
        float df = evv - zvv;
        qout[(size_t)row * D_DIM + tid] = zvv + df;
        rv[tid] = df * df;
        __syncthreads();
        for (int s2r = 128; s2r; s2r >>= 1) {
            if (tid < s2r) rv[tid] += rv[tid + s2r];
            __syncthreads();
        }
        if (tid == 0) {
            atomicAdd(lossAcc, rv[0]);
            atomicAdd(&counts[k], 1.0f);
        }
        __syncthreads();
    }
}

__global__ __launch_bounds__(256) void finalize_kernel(
    const float* __restrict__ counts, const float* __restrict__ lossAcc,
    float* __restrict__ out_loss, float* __restrict__ out_perp,
    int K, float invN, float invND) {
    __shared__ float red[256];
    int t = threadIdx.x;
    float h = 0.f;
    for (int k = t; k < K; k += 256) {
        float p = counts[k] * invN;
        h += p * logf(p + 1e-10f);
    }
    red[t] = h;
    __syncthreads();
    for (int s = 128; s; s >>= 1) {
        if (t < s) red[t] += red[t + s];
        __syncthreads();
    }
    if (t == 0) {
        out_loss[0] = 0.25f * lossAcc[0] * invND;
        out_perp[0] = expf(-red[0]);
    }
}

extern "C" void kernel_launch(void* const* d_in, const int* in_sizes, int n_in,
                              void* d_out, int out_size, void* d_ws, size_t ws_size,
                              hipStream_t stream) {
    const float* z = (const float*)d_in[0];
    const float* emb = (const float*)d_in[1];
    const int N = in_sizes[0] / D_DIM;   // 131072
    const int K = in_sizes[1] / D_DIM;   // 1024
    float* out = (float*)d_out;

    char* ws = (char*)d_ws;
    const size_t EHF_OFF = 0;
    const size_t ESQ_OFF = 512 * 1024;
    const size_t CNT_OFF = ESQ_OFF + 4096;
    const size_t LOSS_OFF = CNT_OFF + 4096;
    const size_t FLC_OFF = LOSS_OFF + 64;
    const size_t FLG_OFF = ESQ_OFF + 16384;

    _Float16* ehf = (_Float16*)(ws + EHF_OFF);
    float* esq = (float*)(ws + ESQ_OFF);
    float* counts = (float*)(ws + CNT_OFF);
    float* lossAcc = (float*)(ws + LOSS_OFF);
    int* flagCount = (int*)(ws + FLC_OFF);
    int* flags = (int*)(ws + FLG_OFF);

    prep_kernel<<<K, 64, 0, stream>>>(emb, ehf, esq, counts, lossAcc, flagCount);
    argmin_fused_kernel<<<N / 128, 256, 0, stream>>>(z, emb, ehf, esq, out + 1,
                                                     counts, lossAcc, flags, flagCount, K);
    rescore_kernel<<<1024, 256, 0, stream>>>(z, emb, esq, flags, flagCount,
                                             out + 1, counts, lossAcc, K);
    finalize_kernel<<<1, 256, 0, stream>>>(counts, lossAcc, out,
                                           out + 1 + (size_t)N * D_DIM, K,
                                           1.0f / (float)N, 1.0f / ((float)N * (float)D_DIM));
}

// Round 6
// 470.026 us; speedup vs baseline: 1.2634x; 1.2634x over previous
//
#include <hip/hip_runtime.h>
#include <hip/hip_bf16.h>

#define D_DIM 256
#define MARGIN 0.12f

typedef __attribute__((ext_vector_type(8))) _Float16 half8v;   // 8 x f16 fragment (4 VGPR)
typedef __attribute__((ext_vector_type(4))) _Float16 half4v;
typedef __attribute__((ext_vector_type(4))) float floatx4;     // MFMA accumulator

// ---------------- ws layout ----------------
// EHF_OFF = 0          : emb_f16 (K*256 f16 = 512KB)
// ESQ_OFF = 512K       : esq     (K floats)
// CNT_OFF = 512K+4K    : counts  (K floats)
// LOSS_OFF= 512K+8K    : lossAcc (float)
// FLC_OFF = 512K+8K+64 : flagCount (int)
// FLG_OFF = 512K+16K   : flags   (N ints)

// emb -> f16, exact fp32 ||e||^2, and zero counts/lossAcc/flagCount (replaces memset).
__global__ __launch_bounds__(64) void prep_kernel(const float* __restrict__ emb,
                                                  _Float16* __restrict__ ehf,
                                                  float* __restrict__ esq,
                                                  float* __restrict__ counts,
                                                  float* __restrict__ lossAcc,
                                                  int* __restrict__ flagCount) {
    int k = blockIdx.x;
    int lane = threadIdx.x;
    float4 v = reinterpret_cast<const float4*>(emb + (size_t)k * D_DIM)[lane];
    half4v h;
    h[0] = (_Float16)v.x; h[1] = (_Float16)v.y; h[2] = (_Float16)v.z; h[3] = (_Float16)v.w;
    *reinterpret_cast<half4v*>(ehf + (size_t)k * D_DIM + lane * 4) = h;
    float s = fmaf(v.x, v.x, fmaf(v.y, v.y, fmaf(v.z, v.z, v.w * v.w)));
    #pragma unroll
    for (int off = 32; off; off >>= 1) s += __shfl_down(s, off, 64);
    if (lane == 0) {
        esq[k] = s;
        counts[k] = 0.f;
        if (k == 0) { *lossAcc = 0.f; *flagCount = 0; }
    }
}

// Stage one 16-code chunk (16 x 256 f16 = 8KB) global->LDS with XOR-swizzled source.
static __device__ __forceinline__ void stage_chunk16(const _Float16* __restrict__ ehf,
                                                     char* lbuf, int c0, int tid) {
    #pragma unroll
    for (int i = 0; i < 2; ++i) {
        int o = i * 4096 + tid * 16;   // per-lane LDS byte offset (linear)
        int code = o >> 9;             // 0..15
        int p = (o >> 4) & 31;         // 16B slot within 512B code row
        int srcSlot = p ^ (code & 7);
        const _Float16* src = ehf + (size_t)(c0 + code) * D_DIM + srcSlot * 8;
        __builtin_amdgcn_global_load_lds(
            (const __attribute__((address_space(1))) unsigned int*)src,
            (__attribute__((address_space(3))) unsigned int*)(lbuf + o),
            16, 0, 0);
    }
}

// Fused: f16-MFMA scores + argmin + (unflagged rows) gather/ST-output/loss/counts.
__global__ __launch_bounds__(256, 4) void argmin_fused_kernel(
    const float* __restrict__ z, const float* __restrict__ emb,
    const _Float16* __restrict__ ehf, const float* __restrict__ esq,
    float* __restrict__ qout, float* __restrict__ counts, float* __restrict__ lossAcc,
    int* __restrict__ flags, int* __restrict__ flagCount, int K)
{
    __shared__ char bstage[2][8192];

    const int tid = threadIdx.x;
    const int lane = tid & 63;
    const int wid = tid >> 6;
    const int l15 = lane & 15;
    const int lk8 = (lane >> 4) << 3;
    const int rowbase = blockIdx.x * 128 + wid * 32;

    stage_chunk16(ehf, &bstage[0][0], 0, tid);

    half8v a0[8], a1[8];
    {
        const float* zr0 = z + (size_t)(rowbase + l15) * D_DIM + lk8;
        const float* zr1 = z + (size_t)(rowbase + 16 + l15) * D_DIM + lk8;
        #pragma unroll
        for (int ks = 0; ks < 8; ++ks) {
            float4 v0 = *reinterpret_cast<const float4*>(zr0 + ks * 32);
            float4 v1 = *reinterpret_cast<const float4*>(zr0 + ks * 32 + 4);
            half8v h;
            h[0] = (_Float16)v0.x; h[1] = (_Float16)v0.y;
            h[2] = (_Float16)v0.z; h[3] = (_Float16)v0.w;
            h[4] = (_Float16)v1.x; h[5] = (_Float16)v1.y;
            h[6] = (_Float16)v1.z; h[7] = (_Float16)v1.w;
            a0[ks] = h;
            float4 w0 = *reinterpret_cast<const float4*>(zr1 + ks * 32);
            float4 w1 = *reinterpret_cast<const float4*>(zr1 + ks * 32 + 4);
            half8v g;
            g[0] = (_Float16)w0.x; g[1] = (_Float16)w0.y;
            g[2] = (_Float16)w0.z; g[3] = (_Float16)w0.w;
            g[4] = (_Float16)w1.x; g[5] = (_Float16)w1.y;
            g[6] = (_Float16)w1.z; g[7] = (_Float16)w1.w;
            a1[ks] = g;
        }
    }

    float best1[2][4], best2[2][4];
    int bidx[2][4];
    #pragma unroll
    for (int mi = 0; mi < 2; ++mi)
        #pragma unroll
        for (int r = 0; r < 4; ++r) { best1[mi][r] = 3.0e38f; best2[mi][r] = 3.0e38f; bidx[mi][r] = 0; }

    const int h3 = l15 & 7;
    const int NT = K / 16;

    for (int t = 0; t < NT; ++t) {
        __syncthreads();
        if (t + 1 < NT) stage_chunk16(ehf, &bstage[(t + 1) & 1][0], (t + 1) * 16, tid);

        const char* lb = &bstage[t & 1][0];
        floatx4 acc0 = (floatx4){0.f, 0.f, 0.f, 0.f};
        floatx4 acc1 = (floatx4){0.f, 0.f, 0.f, 0.f};

        #pragma unroll
        for (int ks = 0; ks < 8; ++ks) {
            int po = ((((lane >> 4) + 4 * ks)) ^ h3) << 4;
            half8v b0 = *reinterpret_cast<const half8v*>(lb + l15 * 512 + po);
            acc0 = __builtin_amdgcn_mfma_f32_16x16x32_f16(a0[ks], b0, acc0, 0, 0, 0);
            acc1 = __builtin_amdgcn_mfma_f32_16x16x32_f16(a1[ks], b0, acc1, 0, 0, 0);
        }

        int c0 = t * 16;
        float e0 = esq[c0 + l15];
        #pragma unroll
        for (int r = 0; r < 4; ++r) {
            float s0 = fmaf(-2.f, acc0[r], e0);
            if (s0 < best1[0][r]) { best2[0][r] = best1[0][r]; best1[0][r] = s0; bidx[0][r] = c0 + l15; }
            else best2[0][r] = fminf(best2[0][r], s0);
            float s1 = fmaf(-2.f, acc1[r], e0);
            if (s1 < best1[1][r]) { best2[1][r] = best1[1][r]; best1[1][r] = s1; bidx[1][r] = c0 + l15; }
            else best2[1][r] = fminf(best2[1][r], s1);
        }
    }

    int packed[2][4];
    #pragma unroll
    for (int mi = 0; mi < 2; ++mi) {
        #pragma unroll
        for (int r = 0; r < 4; ++r) {
            float a1v = best1[mi][r], b2 = best2[mi][r];
            int i = bidx[mi][r];
            #pragma unroll
            for (int off = 8; off; off >>= 1) {
                float oa = __shfl_xor(a1v, off, 16);
                float ob = __shfl_xor(b2, off, 16);
                int oi = __shfl_xor(i, off, 16);
                float m2 = fminf(fmaxf(a1v, oa), fminf(b2, ob));
                if (oa < a1v || (oa == a1v && oi < i)) { a1v = oa; i = oi; }
                b2 = m2;
            }
            bool flg = (b2 - a1v < MARGIN);
            packed[mi][r] = i | (flg ? (int)0x80000000 : 0);
            if (l15 == 0 && flg) {
                int row = rowbase + mi * 16 + (lane >> 4) * 4 + r;
                int p = atomicAdd(flagCount, 1);
                flags[p] = row;
            }
        }
    }

    float ls = 0.f;
    #pragma unroll
    for (int j = 0; j < 32; ++j) {
        const int mi = j >> 4;
        const int r = j & 3;
        const int srcLane = ((j & 15) >> 2) << 4;
        int pk = __shfl(packed[mi][r], srcLane, 64);
        if (pk >= 0) {
            int k = pk;
            int row = rowbase + j;
            float4 zv = *reinterpret_cast<const float4*>(z + (size_t)row * D_DIM + lane * 4);
            float4 ev = *reinterpret_cast<const float4*>(emb + (size_t)k * D_DIM + lane * 4);
            float4 df, o;
            df.x = ev.x - zv.x; df.y = ev.y - zv.y; df.z = ev.z - zv.z; df.w = ev.w - zv.w;
            o.x = zv.x + df.x; o.y = zv.y + df.y; o.z = zv.z + df.z; o.w = zv.w + df.w;
            *reinterpret_cast<float4*>(qout + (size_t)row * D_DIM + lane * 4) = o;
            ls = fmaf(df.x, df.x, ls); ls = fmaf(df.y, df.y, ls);
            ls = fmaf(df.z, df.z, ls); ls = fmaf(df.w, df.w, ls);
            if (lane == 0) atomicAdd(&counts[k], 1.0f);
        }
    }
    #pragma unroll
    for (int off = 32; off; off >>= 1) ls += __shfl_down(ls, off, 64);
    if (lane == 0) atomicAdd(lossAcc, ls);
}

// Tiled exact-fp32 rescore: 16 flagged rows per chunk staged in LDS; each thread
// owns 4 codes (2 passes x 2 codes); winner via packed-u64 min (first-idx ties).
// emb traffic: 1MB per 16 rows instead of 1MB per row.
__global__ __launch_bounds__(256) void rescore_kernel(
    const float* __restrict__ z, const float* __restrict__ emb,
    const float* __restrict__ esq,
    const int* __restrict__ flags, const int* __restrict__ flagCount,
    float* __restrict__ qout, float* __restrict__ counts, float* __restrict__ lossAcc,
    int K)
{
    __shared__ float zs[16][D_DIM];
    __shared__ unsigned long long wbest[4][16];
    __shared__ float lred[4];

    const int tid = threadIdx.x;
    const int lane = tid & 63;
    const int wid = tid >> 6;
    const int cnt = *flagCount;
    const int nchunks = (cnt + 15) >> 4;
    float ls = 0.f;

    for (int c = blockIdx.x; c < nchunks; c += gridDim.x) {
        const int base = c * 16;
        __syncthreads();   // previous chunk's zs/wbest reads complete
        // stage 16 z rows (wave w loads rows w, w+4, w+8, w+12)
        #pragma unroll
        for (int j = 0; j < 4; ++j) {
            int r = wid + j * 4;
            int fi = base + r;
            int row = flags[fi < cnt ? fi : base];   // clamp (dup harmless)
            float4 v = *reinterpret_cast<const float4*>(z + (size_t)row * D_DIM + lane * 4);
            *reinterpret_cast<float4*>(&zs[r][lane * 4]) = v;
        }
        __syncthreads();

        unsigned long long best[16];
        #pragma unroll
        for (int pass = 0; pass < 2; ++pass) {
            int code0 = tid * 4 + pass * 2;
            const float* er0 = emb + (size_t)code0 * D_DIM;
            const float* er1 = er0 + D_DIM;
            float acc[2][16];
            #pragma unroll
            for (int r = 0; r < 16; ++r) { acc[0][r] = 0.f; acc[1][r] = 0.f; }
            for (int d = 0; d < D_DIM; d += 4) {
                float4 e0 = *reinterpret_cast<const float4*>(er0 + d);
                float4 e1 = *reinterpret_cast<const float4*>(er1 + d);
                #pragma unroll
                for (int r = 0; r < 16; ++r) {
                    float4 zv = *reinterpret_cast<const float4*>(&zs[r][d]);
                    acc[0][r] = fmaf(zv.x, e0.x, acc[0][r]);
                    acc[0][r] = fmaf(zv.y, e0.y, acc[0][r]);
                    acc[0][r] = fmaf(zv.z, e0.z, acc[0][r]);
                    acc[0][r] = fmaf(zv.w, e0.w, acc[0][r]);
                    acc[1][r] = fmaf(zv.x, e1.x, acc[1][r]);
                    acc[1][r] = fmaf(zv.y, e1.y, acc[1][r]);
                    acc[1][r] = fmaf(zv.z, e1.z, acc[1][r]);
                    acc[1][r] = fmaf(zv.w, e1.w, acc[1][r]);
                }
            }
            #pragma unroll
            for (int j = 0; j < 2; ++j) {
                int code = code0 + j;
                float ek = esq[code];
                #pragma unroll
                for (int r = 0; r < 16; ++r) {
                    float s = fmaf(-2.f, acc[j][r], ek);
                    unsigned u = __float_as_uint(s);
                    unsigned key = (u & 0x80000000u) ? ~u : (u | 0x80000000u);
                    unsigned long long pk = ((unsigned long long)key << 32) | (unsigned)code;
                    if (pass == 0 && j == 0) best[r] = pk;
                    else best[r] = pk < best[r] ? pk : best[r];
                }
            }
        }

        // reduce across 64 lanes, then across 4 waves
        #pragma unroll
        for (int r = 0; r < 16; ++r) {
            unsigned long long b = best[r];
            #pragma unroll
            for (int off = 32; off; off >>= 1) {
                unsigned long long ob = __shfl_xor(b, off, 64);
                b = ob < b ? ob : b;
            }
            if (lane == 0) wbest[wid][r] = b;
        }
        __syncthreads();
        if (tid < 16) {
            unsigned long long b = wbest[0][tid];
            #pragma unroll
            for (int w = 1; w < 4; ++w) {
                unsigned long long ob = wbest[w][tid];
                b = ob < b ? ob : b;
            }
            wbest[0][tid] = b;
        }
        __syncthreads();

        // epilogue: q write, loss, counts for the (up to) 16 rows
        #pragma unroll
        for (int r = 0; r < 16; ++r) {
            int fi = base + r;
            if (fi < cnt) {
                int row = flags[fi];
                int k = (int)(unsigned)(wbest[0][r] & 0xFFFFFFFFull);
                float zvv = zs[r][tid];
                float evv = emb[(size_t)k * D_DIM + tid];
                float df = evv - zvv;
                qout[(size_t)row * D_DIM + tid] = zvv + df;
                ls = fmaf(df, df, ls);
                if (tid == 0) atomicAdd(&counts[k], 1.0f);
            }
        }
    }

    // one loss reduction for all chunks this block processed
    #pragma unroll
    for (int off = 32; off; off >>= 1) ls += __shfl_down(ls, off, 64);
    if (lane == 0) lred[wid] = ls;
    __syncthreads();
    if (tid == 0) {
        float t = lred[0] + lred[1] + lred[2] + lred[3];
        atomicAdd(lossAcc, t);
    }
}

__global__ __launch_bounds__(256) void finalize_kernel(
    const float* __restrict__ counts, const float* __restrict__ lossAcc,
    float* __restrict__ out_loss, float* __restrict__ out_perp,
    int K, float invN, float invND) {
    __shared__ float red[256];
    int t = threadIdx.x;
    float h = 0.f;
    for (int k = t; k < K; k += 256) {
        float p = counts[k] * invN;
        h += p * logf(p + 1e-10f);
    }
    red[t] = h;
    __syncthreads();
    for (int s = 128; s; s >>= 1) {
        if (t < s) red[t] += red[t + s];
        __syncthreads();
    }
    if (t == 0) {
        out_loss[0] = 0.25f * lossAcc[0] * invND;
        out_perp[0] = expf(-red[0]);
    }
}

extern "C" void kernel_launch(void* const* d_in, const int* in_sizes, int n_in,
                              void* d_out, int out_size, void* d_ws, size_t ws_size,
                              hipStream_t stream) {
    const float* z = (const float*)d_in[0];
    const float* emb = (const float*)d_in[1];
    const int N = in_sizes[0] / D_DIM;   // 131072
    const int K = in_sizes[1] / D_DIM;   // 1024
    float* out = (float*)d_out;

    char* ws = (char*)d_ws;
    const size_t EHF_OFF = 0;
    const size_t ESQ_OFF = 512 * 1024;
    const size_t CNT_OFF = ESQ_OFF + 4096;
    const size_t LOSS_OFF = CNT_OFF + 4096;
    const size_t FLC_OFF = LOSS_OFF + 64;
    const size_t FLG_OFF = ESQ_OFF + 16384;

    _Float16* ehf = (_Float16*)(ws + EHF_OFF);
    float* esq = (float*)(ws + ESQ_OFF);
    float* counts = (float*)(ws + CNT_OFF);
    float* lossAcc = (float*)(ws + LOSS_OFF);
    int* flagCount = (int*)(ws + FLC_OFF);
    int* flags = (int*)(ws + FLG_OFF);

    prep_kernel<<<K, 64, 0, stream>>>(emb, ehf, esq, counts, lossAcc, flagCount);
    argmin_fused_kernel<<<N / 128, 256, 0, stream>>>(z, emb, ehf, esq, out + 1,
                                                     counts, lossAcc, flags, flagCount, K);
    rescore_kernel<<<512, 256, 0, stream>>>(z, emb, esq, flags, flagCount,
                                            out + 1, counts, lossAcc, K);
    finalize_kernel<<<1, 256, 0, stream>>>(counts, lossAcc, out,
                                           out + 1 + (size_t)N * D_DIM, K,
                                           1.0f / (float)N, 1.0f / ((float)N * (float)D_DIM));
}